// Round 7
// baseline (285.520 us; speedup 1.0000x reference)
//
#include <hip/hip_runtime.h>

#define N_NODES 100000
#define E_EDGES 600000
#define LATDIM 128
#define HEAD 4
#define HDIM 32

#define SCAN_NB 98          // 98 blocks x 1024 elems >= N_NODES
#define NCHUNK 391          // ceil(N/256) row chunks
#define QKV_GRID (NCHUNK * 2)

typedef _Float16 f16x8 __attribute__((ext_vector_type(8)));
typedef float    f32x4 __attribute__((ext_vector_type(4)));

__device__ __forceinline__ unsigned f32_to_bf16_rne(float x) {
    unsigned u = __float_as_uint(x);
    u += 0x7fffu + ((u >> 16) & 1u);   // round to nearest even
    return u >> 16;
}

// ---------------------------------------------------------------------------
// Weight prep + workspace zeroing. W[k][c] f32 -> WT[m][c][k] f16 (single
// plane; f16 GEMM error 2^-12 is 8x below the bf16 KV-pack error 2^-9 that
// dominates absmax).
// ---------------------------------------------------------------------------
__global__ __launch_bounds__(256) void wprep_kernel(
    const float* __restrict__ qT, const float* __restrict__ kT,
    const float* __restrict__ vT,
    unsigned short* __restrict__ WT,
    int* __restrict__ counts, unsigned* __restrict__ state)
{
    int g = blockIdx.x * 256 + threadIdx.x;

    // zero counts + scan state (graph replays => re-zero every launch)
    for (int i = g; i < N_NODES; i += SCAN_NB * 256) counts[i] = 0;
    if (g < 128) state[g] = 0u;

    if (g >= 3072) return;
    int m    = g >> 10;          // 0..2
    int rem  = g & 1023;
    int c    = rem >> 3;         // 0..127
    int k0   = (rem & 7) * 16;   // 0..112
    const float* W = (m == 0) ? qT : (m == 1) ? kT : vT;

    unsigned short hv[16];
    #pragma unroll
    for (int j = 0; j < 16; ++j) {
        _Float16 h = (_Float16)W[(size_t)(k0 + j) * 128 + c];   // RNE cvt
        hv[j] = __builtin_bit_cast(unsigned short, h);
    }
    size_t off = (size_t)m * 16384 + (size_t)c * 128 + k0;
    *(uint4*)(WT + off)     = *(const uint4*)&hv[0];
    *(uint4*)(WT + off + 8) = *(const uint4*)&hv[8];
}

// ---------------------------------------------------------------------------
// Kernel A v7: barrier-free f16 MFMA QKV.
//  - grid = 2 col-halves x 391 row-chunks (256 rows each); block = 256 thr.
//  - stage the block's 64-col half of ALL THREE weight matrices once into
//    48 KiB LDS (XOR-swizzled), ONE __syncthreads, then each wave processes
//    4 independent 16-row tiles with zero synchronization:
//    A loads global->reg (f32->f16 convert), 48 ds_read_b128, 48 MFMA,
//    Q f32 + KV bf16-packed scalar stores.
//  - 48 KiB LDS -> 3 blocks/CU = 12 waves: latency hidden by TLP, no
//    barrier drains (r2-r6 plateau was ~15 vmcnt(0) drains per block).
//  - edge histogram fused at the tail (fire-and-forget atomics).
// ---------------------------------------------------------------------------
__global__ __launch_bounds__(256) void qkv_mfma_kernel(
    const float* __restrict__ embeds,
    const unsigned short* __restrict__ WT,
    const int* __restrict__ rows,
    int* __restrict__ counts,
    float* __restrict__ Q, unsigned* __restrict__ KV)
{
    __shared__ __align__(16) char smem[49152];   // 3 panels x 16 KiB

    const int tid  = threadIdx.x;
    const int half = blockIdx.x & 1;             // col half: cols half*64..+63
    const int chunk = blockIdx.x >> 1;           // 256-row chunk

    // ---- stage B: 3 matrices x 64 cols x 128 k (f16), swizzled ----
    #pragma unroll
    for (int it = 0; it < 12; ++it) {
        const int m   = it >> 2;                       // 0..2 (compile-time)
        const int idx = (it & 3) * 256 + tid;          // 16B chunk in panel
        uint4 v = *(const uint4*)((const char*)(WT + (size_t)m * 16384
                                                   + (size_t)half * 8192) + idx * 16);
        int c = idx >> 4;                              // col 0..63
        int b = (c * 256 + (idx & 15) * 16) ^ ((c & 7) << 4);
        *(uint4*)(smem + m * 16384 + b) = v;
    }
    __syncthreads();        // the ONLY barrier in this kernel

    const int lane = tid & 63;
    const int wv   = tid >> 6;         // 0..3
    const int lrow = lane & 15;
    const int kg   = lane >> 4;        // 0..3

    for (int t = 0; t < 4; ++t) {
        const int rowT = chunk * 256 + t * 64 + wv * 16;
        const int arow = rowT + lrow;
        const bool rok = arow < N_NODES;

        // ---- A fragments: global f32 -> reg -> f16 (MFMA A layout:
        //      lane holds A[row=lane&15][k = kk*32 + (lane>>4)*8 + j]) ----
        f16x8 a[4];
        #pragma unroll
        for (int kk = 0; kk < 4; ++kk) {
            float4 u0 = make_float4(0.f, 0.f, 0.f, 0.f), u1 = u0;
            if (rok) {
                const float* p = embeds + (size_t)arow * 128 + kk * 32 + kg * 8;
                u0 = *(const float4*)p;
                u1 = *(const float4*)(p + 4);
            }
            a[kk][0] = (_Float16)u0.x; a[kk][1] = (_Float16)u0.y;
            a[kk][2] = (_Float16)u0.z; a[kk][3] = (_Float16)u0.w;
            a[kk][4] = (_Float16)u1.x; a[kk][5] = (_Float16)u1.y;
            a[kk][6] = (_Float16)u1.z; a[kk][7] = (_Float16)u1.w;
        }

#define MFMA_M(ACC, M) do {                                                      \
        _Pragma("unroll")                                                        \
        for (int kk = 0; kk < 4; ++kk) {                                         \
            _Pragma("unroll")                                                    \
            for (int n = 0; n < 4; ++n) {                                        \
                int col  = n * 16 + lrow;                                        \
                int byte = (col * 256 + kk * 64 + kg * 16) ^ ((lrow & 7) << 4);  \
                f16x8 b = __builtin_bit_cast(f16x8,                              \
                          *(const uint4*)(smem + (M) * 16384 + byte));           \
                ACC[n] = __builtin_amdgcn_mfma_f32_16x16x32_f16(a[kk], b, ACC[n], 0, 0, 0); \
            }                                                                    \
        }                                                                        \
    } while (0)

        // ---- m=0: Q ----
        f32x4 kreg[4];
        {
            f32x4 acc[4] = { {0.f,0.f,0.f,0.f}, {0.f,0.f,0.f,0.f},
                             {0.f,0.f,0.f,0.f}, {0.f,0.f,0.f,0.f} };
            MFMA_M(acc, 0);
            #pragma unroll
            for (int n = 0; n < 4; ++n)
                #pragma unroll
                for (int j = 0; j < 4; ++j) {
                    int gr  = rowT + kg * 4 + j;
                    int col = half * 64 + n * 16 + lrow;
                    if (gr < N_NODES) Q[(size_t)gr * 128 + col] = acc[n][j];
                }
        }
        // ---- m=1: K kept in regs ----
        {
            f32x4 acc[4] = { {0.f,0.f,0.f,0.f}, {0.f,0.f,0.f,0.f},
                             {0.f,0.f,0.f,0.f}, {0.f,0.f,0.f,0.f} };
            MFMA_M(acc, 1);
            kreg[0] = acc[0]; kreg[1] = acc[1]; kreg[2] = acc[2]; kreg[3] = acc[3];
        }
        // ---- m=2: V -> pack (k,v) bf16 pair ----
        {
            f32x4 acc[4] = { {0.f,0.f,0.f,0.f}, {0.f,0.f,0.f,0.f},
                             {0.f,0.f,0.f,0.f}, {0.f,0.f,0.f,0.f} };
            MFMA_M(acc, 2);
            #pragma unroll
            for (int n = 0; n < 4; ++n)
                #pragma unroll
                for (int j = 0; j < 4; ++j) {
                    int gr  = rowT + kg * 4 + j;
                    int col = half * 64 + n * 16 + lrow;
                    if (gr < N_NODES) {
                        unsigned pk = f32_to_bf16_rne(kreg[n][j])
                                    | (f32_to_bf16_rne(acc[n][j]) << 16);
                        KV[(size_t)gr * 128 + col] = pk;
                    }
                }
        }
#undef MFMA_M
    }

    // ---- fused edge histogram at the tail ----
    for (int e = blockIdx.x * 256 + tid; e < E_EDGES; e += QKV_GRID * 256)
        atomicAdd(&counts[rows[e]], 1);
}

// ---------------------------------------------------------------------------
// Single-pass exclusive scan with decoupled lookback.
// ---------------------------------------------------------------------------
__global__ __launch_bounds__(256) void scan_lb_kernel(
    const int* __restrict__ counts, int* __restrict__ starts,
    int* __restrict__ cursor, unsigned* __restrict__ state)
{
    __shared__ int s[256];
    __shared__ int bcast;
    int b = blockIdx.x, t = threadIdx.x;
    int base = b * 1024 + t * 4;
    int v0 = (base + 0 < N_NODES) ? counts[base + 0] : 0;
    int v1 = (base + 1 < N_NODES) ? counts[base + 1] : 0;
    int v2 = (base + 2 < N_NODES) ? counts[base + 2] : 0;
    int v3 = (base + 3 < N_NODES) ? counts[base + 3] : 0;
    int local = v0 + v1 + v2 + v3;
    s[t] = local;
    __syncthreads();
    for (int off = 1; off < 256; off <<= 1) {
        int x = (t >= off) ? s[t - off] : 0;
        __syncthreads();
        s[t] += x;
        __syncthreads();
    }
    int incl  = s[t];
    int excl  = incl - local;
    int total = s[255];

    if (t == 0) {
        int sum = 0;
        if (b == 0) {
            atomicExch(&state[0], ((unsigned)total << 2) | 2u);
        } else {
            atomicExch(&state[b], ((unsigned)total << 2) | 1u);
            int i = b - 1;
            while (true) {
                unsigned w = atomicAdd(&state[i], 0u);   // atomic load
                unsigned st = w & 3u;
                if (st == 0u) continue;
                sum += (int)(w >> 2);
                if (st == 2u) break;
                --i;
            }
            atomicExch(&state[b], ((unsigned)(sum + total) << 2) | 2u);
        }
        bcast = sum;
    }
    __syncthreads();
    int e = excl + bcast;
    if (base + 0 < N_NODES) { starts[base + 0] = e;                cursor[base + 0] = e; }
    if (base + 1 < N_NODES) { starts[base + 1] = e + v0;           cursor[base + 1] = e + v0; }
    if (base + 2 < N_NODES) { starts[base + 2] = e + v0 + v1;      cursor[base + 2] = e + v0 + v1; }
    if (base + 3 < N_NODES) { starts[base + 3] = e + v0 + v1 + v2; cursor[base + 3] = e + v0 + v1 + v2; }
}

__global__ __launch_bounds__(256) void scatter_kernel(
    const int* __restrict__ rows, const int* __restrict__ cols,
    int* __restrict__ cursor, int* __restrict__ csrCols)
{
    int e = blockIdx.x * 256 + threadIdx.x;
    if (e >= E_EDGES) return;
    int pos = atomicAdd(&cursor[rows[e]], 1);
    csrCols[pos] = cols[e];
}

// ---------------------------------------------------------------------------
// Kernel B: fused attention + aggregation.
// 32 threads/node, 4 dims/thread (uint4 KV load = 16B/lane).
// ---------------------------------------------------------------------------
__global__ __launch_bounds__(256) void att_agg_kernel(
    const float* __restrict__ Q, const unsigned* __restrict__ KV,
    const float* __restrict__ filt,
    const int* __restrict__ starts, const int* __restrict__ counts,
    const int* __restrict__ csrCols,
    float* __restrict__ out)
{
    int t = threadIdx.x;
    int node = blockIdx.x * 8 + (t >> 5);
    if (node >= N_NODES) return;
    int lane = t & 31;
    int h = lane >> 3;

    float4 q = ((const float4*)(Q + (size_t)node * 128))[lane];
    int s   = starts[node];
    int cnt = counts[node];

    float norm = 0.f;
    float ax = 0.f, ay = 0.f, az = 0.f, aw = 0.f;

    int i = 0;
    for (; i + 2 <= cnt; i += 2) {
        int c0 = csrCols[s + i];
        int c1 = csrCols[s + i + 1];
        uint4 kv0 = ((const uint4*)KV)[(size_t)c0 * 32 + lane];
        uint4 kv1 = ((const uint4*)KV)[(size_t)c1 * 32 + lane];
        float f0 = filt[c0 * HEAD + h];
        float f1 = filt[c1 * HEAD + h];

        float k0x = __uint_as_float(kv0.x << 16), v0x = __uint_as_float(kv0.x & 0xffff0000u);
        float k0y = __uint_as_float(kv0.y << 16), v0y = __uint_as_float(kv0.y & 0xffff0000u);
        float k0z = __uint_as_float(kv0.z << 16), v0z = __uint_as_float(kv0.z & 0xffff0000u);
        float k0w = __uint_as_float(kv0.w << 16), v0w = __uint_as_float(kv0.w & 0xffff0000u);
        float k1x = __uint_as_float(kv1.x << 16), v1x = __uint_as_float(kv1.x & 0xffff0000u);
        float k1y = __uint_as_float(kv1.y << 16), v1y = __uint_as_float(kv1.y & 0xffff0000u);
        float k1z = __uint_as_float(kv1.z << 16), v1z = __uint_as_float(kv1.z & 0xffff0000u);
        float k1w = __uint_as_float(kv1.w << 16), v1w = __uint_as_float(kv1.w & 0xffff0000u);

        float p0 = q.x * k0x + q.y * k0y + q.z * k0z + q.w * k0w;
        float p1 = q.x * k1x + q.y * k1y + q.z * k1z + q.w * k1w;
        p0 += __shfl_xor(p0, 1);   p1 += __shfl_xor(p1, 1);
        p0 += __shfl_xor(p0, 2);   p1 += __shfl_xor(p1, 2);
        p0 += __shfl_xor(p0, 4);   p1 += __shfl_xor(p1, 4);

        float w0 = __expf(fminf(fmaxf(p0, -10.f), 10.f) + f0);
        float w1 = __expf(fminf(fmaxf(p1, -10.f), 10.f) + f1);
        norm += w0 + w1;
        ax += w0 * v0x + w1 * v1x;
        ay += w0 * v0y + w1 * v1y;
        az += w0 * v0z + w1 * v1z;
        aw += w0 * v0w + w1 * v1w;
    }
    if (i < cnt) {
        int c0 = csrCols[s + i];
        uint4 kv0 = ((const uint4*)KV)[(size_t)c0 * 32 + lane];
        float f0 = filt[c0 * HEAD + h];
        float k0x = __uint_as_float(kv0.x << 16), v0x = __uint_as_float(kv0.x & 0xffff0000u);
        float k0y = __uint_as_float(kv0.y << 16), v0y = __uint_as_float(kv0.y & 0xffff0000u);
        float k0z = __uint_as_float(kv0.z << 16), v0z = __uint_as_float(kv0.z & 0xffff0000u);
        float k0w = __uint_as_float(kv0.w << 16), v0w = __uint_as_float(kv0.w & 0xffff0000u);
        float p0 = q.x * k0x + q.y * k0y + q.z * k0z + q.w * k0w;
        p0 += __shfl_xor(p0, 1);
        p0 += __shfl_xor(p0, 2);
        p0 += __shfl_xor(p0, 4);
        float w0 = __expf(fminf(fmaxf(p0, -10.f), 10.f) + f0);
        norm += w0;
        ax += w0 * v0x; ay += w0 * v0y; az += w0 * v0z; aw += w0 * v0w;
    }
    float inv = 1.0f / (norm + 1e-8f);
    ((float4*)(out + (size_t)node * 128))[lane] =
        make_float4(ax * inv, ay * inv, az * inv, aw * inv);
}

// ---------------------------------------------------------------------------
extern "C" void kernel_launch(void* const* d_in, const int* in_sizes, int n_in,
                              void* d_out, int out_size, void* d_ws, size_t ws_size,
                              hipStream_t stream) {
    const float* embeds = (const float*)d_in[0];
    const float* qT     = (const float*)d_in[1];
    const float* kT     = (const float*)d_in[2];
    const float* vT     = (const float*)d_in[3];
    const float* filt   = (const float*)d_in[4];
    const int*   rows   = (const int*)d_in[5];
    const int*   cols   = (const int*)d_in[6];
    float*       out    = (float*)d_out;

    // Workspace: Q: N*128 f32 | KV: N*128 u32 | counts,starts,cursor: N i32 |
    //            csrCols: E i32 | state: 128 u32
    float*    Q  = (float*)d_ws;
    unsigned* KV = (unsigned*)(Q + (size_t)N_NODES * 128);
    int* counts    = (int*)(KV + (size_t)N_NODES * 128);
    int* starts    = counts + N_NODES;
    int* cursor    = starts + N_NODES;
    int* csrCols   = cursor + N_NODES;
    unsigned* state = (unsigned*)(csrCols + E_EDGES);

    // f16 weight plane ALIASES the csrCols region (96 KiB of 2.34 MiB).
    // Stream-ordered safe: wprep+qkv complete before scatter writes csrCols.
    unsigned short* WT = (unsigned short*)csrCols;

    wprep_kernel<<<SCAN_NB, 256, 0, stream>>>(qT, kT, vT, WT, counts, state);
    qkv_mfma_kernel<<<QKV_GRID, 256, 0, stream>>>(
        embeds, WT, rows, counts, Q, KV);
    scan_lb_kernel<<<SCAN_NB, 256, 0, stream>>>(counts, starts, cursor, state);
    scatter_kernel<<<(E_EDGES + 255) / 256, 256, 0, stream>>>(rows, cols, cursor, csrCols);
    att_agg_kernel<<<(N_NODES + 7) / 8, 256, 0, stream>>>(
        Q, KV, filt, starts, counts, csrCols, out);
}

// Round 8
// 251.130 us; speedup vs baseline: 1.1369x; 1.1369x over previous
//
#include <hip/hip_runtime.h>

#define N_NODES 100000
#define E_EDGES 600000
#define LATDIM 128
#define HEAD 4
#define HDIM 32

#define SCAN_NB 98          // 98 blocks x 1024 elems >= N_NODES

typedef _Float16 f16x8 __attribute__((ext_vector_type(8)));
typedef float    f32x4 __attribute__((ext_vector_type(4)));

__device__ __forceinline__ unsigned f32_to_bf16_rne(float x) {
    unsigned u = __float_as_uint(x);
    u += 0x7fffu + ((u >> 16) & 1u);   // round to nearest even
    return u >> 16;
}

// ---------------------------------------------------------------------------
// Weight prep + workspace zeroing. W[k][c] f32 -> WT[m][c][k] f16.
// f16 GEMM (err 2^-12) validated in r7: absmax 0.0703 < bf16-pack-dominated.
// ---------------------------------------------------------------------------
__global__ __launch_bounds__(256) void wprep_kernel(
    const float* __restrict__ qT, const float* __restrict__ kT,
    const float* __restrict__ vT,
    unsigned short* __restrict__ WT,
    int* __restrict__ counts, unsigned* __restrict__ state)
{
    int g = blockIdx.x * 256 + threadIdx.x;

    // zero counts + scan state (graph replays => re-zero every launch)
    for (int i = g; i < N_NODES; i += SCAN_NB * 256) counts[i] = 0;
    if (g < 128) state[g] = 0u;

    if (g >= 3072) return;
    int m    = g >> 10;          // 0..2
    int rem  = g & 1023;
    int c    = rem >> 3;         // 0..127
    int k0   = (rem & 7) * 16;   // 0..112
    const float* W = (m == 0) ? qT : (m == 1) ? kT : vT;

    unsigned short hv[16];
    #pragma unroll
    for (int j = 0; j < 16; ++j) {
        _Float16 h = (_Float16)W[(size_t)(k0 + j) * 128 + c];   // RNE cvt
        hv[j] = __builtin_bit_cast(unsigned short, h);
    }
    size_t off = (size_t)m * 16384 + (size_t)c * 128 + k0;
    *(uint4*)(WT + off)     = *(const uint4*)&hv[0];
    *(uint4*)(WT + off + 8) = *(const uint4*)&hv[8];
}

// ---------------------------------------------------------------------------
// Kernel A v8: proven r5/r6 shell + validated f16 single-product MFMA.
//  - 256 thr / 64 rows; A staged f16 16 KiB (region R0), B panels f16 16 KiB
//    double-buffered: R0 (overlays A after frag hoist) <-> R1. 32 KiB LDS
//    -> 4 blocks/CU (VGPR ~100). ONE barrier per panel (8 total, was 13).
//  - MFMA/panel: 16 (was 48); staged bytes/panel: 16 KiB (was 32 KiB).
//  - named scalar prefetch regs (rule #20); straight-line panels.
//  - edge histogram fused at the tail.
// ---------------------------------------------------------------------------
__global__ __launch_bounds__(256) void qkv_mfma_kernel(
    const float* __restrict__ embeds,
    const unsigned short* __restrict__ WT,
    const int* __restrict__ rows,
    int* __restrict__ counts,
    float* __restrict__ Q, unsigned* __restrict__ KV)
{
    __shared__ __align__(16) char smem[32768];
    char* R0 = smem;               // A (stage+hoist), then B buffer
    char* R1 = smem + 16384;       // B buffer

    const int tid = threadIdx.x;
    const int rowBase = blockIdx.x * 64;

    uint4 pb0, pb1, pb2, pb3;      // named scalars: cannot be promoted

#define PF(MN, HN) do {                                                          \
        const char* _s = (const char*)(WT + (size_t)(MN) * 16384                 \
                                          + (size_t)(HN) * 8192);                \
        pb0 = *(const uint4*)(_s + (size_t)(0 * 256 + tid) * 16);                \
        pb1 = *(const uint4*)(_s + (size_t)(1 * 256 + tid) * 16);                \
        pb2 = *(const uint4*)(_s + (size_t)(2 * 256 + tid) * 16);                \
        pb3 = *(const uint4*)(_s + (size_t)(3 * 256 + tid) * 16);                \
    } while (0)

#define COMMIT(R) do {                                                           \
        { int _i = 0 * 256 + tid; int _c = _i >> 4;                              \
          int _s = (_c * 256 + (_i & 15) * 16) ^ ((_c & 7) << 4);                \
          *(uint4*)((R) + _s) = pb0; }                                           \
        { int _i = 1 * 256 + tid; int _c = _i >> 4;                              \
          int _s = (_c * 256 + (_i & 15) * 16) ^ ((_c & 7) << 4);                \
          *(uint4*)((R) + _s) = pb1; }                                           \
        { int _i = 2 * 256 + tid; int _c = _i >> 4;                              \
          int _s = (_c * 256 + (_i & 15) * 16) ^ ((_c & 7) << 4);                \
          *(uint4*)((R) + _s) = pb2; }                                           \
        { int _i = 3 * 256 + tid; int _c = _i >> 4;                              \
          int _s = (_c * 256 + (_i & 15) * 16) ^ ((_c & 7) << 4);                \
          *(uint4*)((R) + _s) = pb3; }                                           \
    } while (0)

#define MFMA_M(ACC, R) do {                                                      \
        _Pragma("unroll")                                                        \
        for (int kk = 0; kk < 4; ++kk) {                                         \
            _Pragma("unroll")                                                    \
            for (int n = 0; n < 4; ++n) {                                        \
                int col  = n * 16 + lrow;                                        \
                int byte = (col * 256 + kk * 64 + kg * 16) ^ ((lrow & 7) << 4);  \
                f16x8 b = __builtin_bit_cast(f16x8, *(const uint4*)((R) + byte)); \
                ACC[n] = __builtin_amdgcn_mfma_f32_16x16x32_f16(a[kk], b, ACC[n], 0, 0, 0); \
            }                                                                    \
        }                                                                        \
    } while (0)

#define ZACC(ACC) f32x4 ACC[4] = { {0.f,0.f,0.f,0.f}, {0.f,0.f,0.f,0.f},         \
                                   {0.f,0.f,0.f,0.f}, {0.f,0.f,0.f,0.f} }

#define STORE_Q(ACC, H) do {                                                     \
        _Pragma("unroll")                                                        \
        for (int n = 0; n < 4; ++n)                                              \
        _Pragma("unroll")                                                        \
        for (int j = 0; j < 4; ++j) {                                            \
            int gr  = rowBase + wv * 16 + kg * 4 + j;                            \
            int col = (H) * 64 + n * 16 + lrow;                                  \
            if (gr < N_NODES) Q[(size_t)gr * 128 + col] = ACC[n][j];             \
        }                                                                        \
    } while (0)

#define STORE_KV(ACC, H) do {                                                    \
        _Pragma("unroll")                                                        \
        for (int n = 0; n < 4; ++n)                                              \
        _Pragma("unroll")                                                        \
        for (int j = 0; j < 4; ++j) {                                            \
            int gr  = rowBase + wv * 16 + kg * 4 + j;                            \
            int col = (H) * 64 + n * 16 + lrow;                                  \
            if (gr < N_NODES) {                                                  \
                unsigned pk = f32_to_bf16_rne(kreg[n][j])                        \
                            | (f32_to_bf16_rne(ACC[n][j]) << 16);                \
                KV[(size_t)gr * 128 + col] = pk;                                 \
            }                                                                    \
        }                                                                        \
    } while (0)

    // ---- prefetch B(m0,h0): overlaps the whole A-stage ----
    PF(0, 0);

    // ---- stage A: embeds f32 -> f16, swizzled into R0 (16 KiB) ----
    #pragma unroll
    for (int it = 0; it < 4; ++it) {
        int idx = it * 256 + tid;          // 16B chunk id, 0..1023
        int r   = idx >> 4;                // row 0..63
        int c16 = idx & 15;                // 16B chunk within row (8 f16)
        int gr  = rowBase + r;
        float4 u0 = make_float4(0.f, 0.f, 0.f, 0.f), u1 = u0;
        if (gr < N_NODES) {
            const float* p = embeds + (size_t)gr * 128 + c16 * 8;
            u0 = *(const float4*)p;
            u1 = *(const float4*)(p + 4);
        }
        f16x8 v;
        v[0] = (_Float16)u0.x; v[1] = (_Float16)u0.y;
        v[2] = (_Float16)u0.z; v[3] = (_Float16)u0.w;
        v[4] = (_Float16)u1.x; v[5] = (_Float16)u1.y;
        v[6] = (_Float16)u1.z; v[7] = (_Float16)u1.w;
        int byte = (r * 256 + c16 * 16) ^ ((r & 7) << 4);
        *(uint4*)(R0 + byte) = __builtin_bit_cast(uint4, v);
    }
    __syncthreads();                                   // sync1: A staged

    const int lane = tid & 63;
    const int wv   = tid >> 6;         // 0..3 (wave -> 16-row tile)
    const int lrow = lane & 15;
    const int kg   = lane >> 4;        // 0..3

    // ---- phase X: hoist A frags from R0; commit B(m0,h0) -> R1 ----
    f16x8 a[4];
    {
        const int arow = wv * 16 + lrow;
        #pragma unroll
        for (int kk = 0; kk < 4; ++kk) {
            int byte = (arow * 256 + kk * 64 + kg * 16) ^ ((lrow & 7) << 4);
            a[kk] = __builtin_bit_cast(f16x8, *(const uint4*)(R0 + byte));
        }
    }
    COMMIT(R1);
    __syncthreads();                                   // sync2: R1 ready, A dead

    f32x4 kreg[4];

    // ---- p0: Q h0 (R1); PF m1,h0 -> commit R0 ----
    {
        PF(1, 0); ZACC(acc);
        MFMA_M(acc, R1);
        STORE_Q(acc, 0);
        COMMIT(R0); __syncthreads();
    }
    // ---- p1: K h0 (R0); PF m2,h0 -> commit R1 ----
    {
        PF(2, 0); ZACC(acc);
        MFMA_M(acc, R0);
        kreg[0] = acc[0]; kreg[1] = acc[1]; kreg[2] = acc[2]; kreg[3] = acc[3];
        COMMIT(R1); __syncthreads();
    }
    // ---- p2: V h0 -> KV (R1); PF m0,h1 -> commit R0 ----
    {
        PF(0, 1); ZACC(acc);
        MFMA_M(acc, R1);
        STORE_KV(acc, 0);
        COMMIT(R0); __syncthreads();
    }
    // ---- p3: Q h1 (R0); PF m1,h1 -> commit R1 ----
    {
        PF(1, 1); ZACC(acc);
        MFMA_M(acc, R0);
        STORE_Q(acc, 1);
        COMMIT(R1); __syncthreads();
    }
    // ---- p4: K h1 (R1); PF m2,h1 -> commit R0 ----
    {
        PF(2, 1); ZACC(acc);
        MFMA_M(acc, R1);
        kreg[0] = acc[0]; kreg[1] = acc[1]; kreg[2] = acc[2]; kreg[3] = acc[3];
        COMMIT(R0); __syncthreads();
    }
    // ---- p5: V h1 -> KV (R0) ----
    {
        ZACC(acc);
        MFMA_M(acc, R0);
        STORE_KV(acc, 1);
    }

    // ---- fused edge histogram at the tail (fire-and-forget atomics) ----
    for (int e = blockIdx.x * 256 + tid; e < E_EDGES; e += gridDim.x * 256)
        atomicAdd(&counts[rows[e]], 1);

#undef PF
#undef COMMIT
#undef MFMA_M
#undef ZACC
#undef STORE_Q
#undef STORE_KV
}

// ---------------------------------------------------------------------------
// Single-pass exclusive scan with decoupled lookback.
// ---------------------------------------------------------------------------
__global__ __launch_bounds__(256) void scan_lb_kernel(
    const int* __restrict__ counts, int* __restrict__ starts,
    int* __restrict__ cursor, unsigned* __restrict__ state)
{
    __shared__ int s[256];
    __shared__ int bcast;
    int b = blockIdx.x, t = threadIdx.x;
    int base = b * 1024 + t * 4;
    int v0 = (base + 0 < N_NODES) ? counts[base + 0] : 0;
    int v1 = (base + 1 < N_NODES) ? counts[base + 1] : 0;
    int v2 = (base + 2 < N_NODES) ? counts[base + 2] : 0;
    int v3 = (base + 3 < N_NODES) ? counts[base + 3] : 0;
    int local = v0 + v1 + v2 + v3;
    s[t] = local;
    __syncthreads();
    for (int off = 1; off < 256; off <<= 1) {
        int x = (t >= off) ? s[t - off] : 0;
        __syncthreads();
        s[t] += x;
        __syncthreads();
    }
    int incl  = s[t];
    int excl  = incl - local;
    int total = s[255];

    if (t == 0) {
        int sum = 0;
        if (b == 0) {
            atomicExch(&state[0], ((unsigned)total << 2) | 2u);
        } else {
            atomicExch(&state[b], ((unsigned)total << 2) | 1u);
            int i = b - 1;
            while (true) {
                unsigned w = atomicAdd(&state[i], 0u);   // atomic load
                unsigned st = w & 3u;
                if (st == 0u) continue;
                sum += (int)(w >> 2);
                if (st == 2u) break;
                --i;
            }
            atomicExch(&state[b], ((unsigned)(sum + total) << 2) | 2u);
        }
        bcast = sum;
    }
    __syncthreads();
    int e = excl + bcast;
    if (base + 0 < N_NODES) { starts[base + 0] = e;                cursor[base + 0] = e; }
    if (base + 1 < N_NODES) { starts[base + 1] = e + v0;           cursor[base + 1] = e + v0; }
    if (base + 2 < N_NODES) { starts[base + 2] = e + v0 + v1;      cursor[base + 2] = e + v0 + v1; }
    if (base + 3 < N_NODES) { starts[base + 3] = e + v0 + v1 + v2; cursor[base + 3] = e + v0 + v1 + v2; }
}

__global__ __launch_bounds__(256) void scatter_kernel(
    const int* __restrict__ rows, const int* __restrict__ cols,
    int* __restrict__ cursor, int* __restrict__ csrCols)
{
    int e = blockIdx.x * 256 + threadIdx.x;
    if (e >= E_EDGES) return;
    int pos = atomicAdd(&cursor[rows[e]], 1);
    csrCols[pos] = cols[e];
}

// ---------------------------------------------------------------------------
// Kernel B: fused attention + aggregation.
// 32 threads/node, 4 dims/thread; v8: 4-edge unroll (4 gathers in flight).
// ---------------------------------------------------------------------------
__global__ __launch_bounds__(256) void att_agg_kernel(
    const float* __restrict__ Q, const unsigned* __restrict__ KV,
    const float* __restrict__ filt,
    const int* __restrict__ starts, const int* __restrict__ counts,
    const int* __restrict__ csrCols,
    float* __restrict__ out)
{
    int t = threadIdx.x;
    int node = blockIdx.x * 8 + (t >> 5);
    if (node >= N_NODES) return;
    int lane = t & 31;
    int h = lane >> 3;

    float4 q = ((const float4*)(Q + (size_t)node * 128))[lane];
    int s   = starts[node];
    int cnt = counts[node];

    float norm = 0.f;
    float ax = 0.f, ay = 0.f, az = 0.f, aw = 0.f;

#define EDGE_BODY(KVU, F)                                                     \
    {                                                                          \
        float kx = __uint_as_float((KVU).x << 16), vx = __uint_as_float((KVU).x & 0xffff0000u); \
        float ky = __uint_as_float((KVU).y << 16), vy = __uint_as_float((KVU).y & 0xffff0000u); \
        float kz = __uint_as_float((KVU).z << 16), vz = __uint_as_float((KVU).z & 0xffff0000u); \
        float kw = __uint_as_float((KVU).w << 16), vw = __uint_as_float((KVU).w & 0xffff0000u); \
        float p = q.x * kx + q.y * ky + q.z * kz + q.w * kw;                   \
        p += __shfl_xor(p, 1);                                                 \
        p += __shfl_xor(p, 2);                                                 \
        p += __shfl_xor(p, 4);                                                 \
        float w = __expf(fminf(fmaxf(p, -10.f), 10.f) + (F));                  \
        norm += w;                                                             \
        ax += w * vx; ay += w * vy; az += w * vz; aw += w * vw;                \
    }

    int i = 0;
    for (; i + 4 <= cnt; i += 4) {
        int c0 = csrCols[s + i];
        int c1 = csrCols[s + i + 1];
        int c2 = csrCols[s + i + 2];
        int c3 = csrCols[s + i + 3];
        uint4 kv0 = ((const uint4*)KV)[(size_t)c0 * 32 + lane];
        uint4 kv1 = ((const uint4*)KV)[(size_t)c1 * 32 + lane];
        uint4 kv2 = ((const uint4*)KV)[(size_t)c2 * 32 + lane];
        uint4 kv3 = ((const uint4*)KV)[(size_t)c3 * 32 + lane];
        float f0 = filt[c0 * HEAD + h];
        float f1 = filt[c1 * HEAD + h];
        float f2 = filt[c2 * HEAD + h];
        float f3 = filt[c3 * HEAD + h];
        EDGE_BODY(kv0, f0);
        EDGE_BODY(kv1, f1);
        EDGE_BODY(kv2, f2);
        EDGE_BODY(kv3, f3);
    }
    for (; i < cnt; ++i) {
        int c0 = csrCols[s + i];
        uint4 kv0 = ((const uint4*)KV)[(size_t)c0 * 32 + lane];
        float f0 = filt[c0 * HEAD + h];
        EDGE_BODY(kv0, f0);
    }
#undef EDGE_BODY

    float inv = 1.0f / (norm + 1e-8f);
    ((float4*)(out + (size_t)node * 128))[lane] =
        make_float4(ax * inv, ay * inv, az * inv, aw * inv);
}

// ---------------------------------------------------------------------------
extern "C" void kernel_launch(void* const* d_in, const int* in_sizes, int n_in,
                              void* d_out, int out_size, void* d_ws, size_t ws_size,
                              hipStream_t stream) {
    const float* embeds = (const float*)d_in[0];
    const float* qT     = (const float*)d_in[1];
    const float* kT     = (const float*)d_in[2];
    const float* vT     = (const float*)d_in[3];
    const float* filt   = (const float*)d_in[4];
    const int*   rows   = (const int*)d_in[5];
    const int*   cols   = (const int*)d_in[6];
    float*       out    = (float*)d_out;

    // Workspace: Q: N*128 f32 | KV: N*128 u32 | counts,starts,cursor: N i32 |
    //            csrCols: E i32 | state: 128 u32
    float*    Q  = (float*)d_ws;
    unsigned* KV = (unsigned*)(Q + (size_t)N_NODES * 128);
    int* counts    = (int*)(KV + (size_t)N_NODES * 128);
    int* starts    = counts + N_NODES;
    int* cursor    = starts + N_NODES;
    int* csrCols   = cursor + N_NODES;
    unsigned* state = (unsigned*)(csrCols + E_EDGES);

    // f16 weight plane ALIASES the csrCols region (96 KiB of 2.34 MiB).
    // Stream-ordered safe: wprep+qkv complete before scatter writes csrCols.
    unsigned short* WT = (unsigned short*)csrCols;

    wprep_kernel<<<SCAN_NB, 256, 0, stream>>>(qT, kT, vT, WT, counts, state);
    qkv_mfma_kernel<<<(N_NODES + 63) / 64, 256, 0, stream>>>(
        embeds, WT, rows, counts, Q, KV);
    scan_lb_kernel<<<SCAN_NB, 256, 0, stream>>>(counts, starts, cursor, state);
    scatter_kernel<<<(E_EDGES + 255) / 256, 256, 0, stream>>>(rows, cols, cursor, csrCols);
    att_agg_kernel<<<(N_NODES + 7) / 8, 256, 0, stream>>>(
        Q, KV, filt, starts, counts, csrCols, out);
}